// Round 10
// baseline (334.078 us; speedup 1.0000x reference)
//
#include <hip/hip_runtime.h>
#include <hip/hip_bf16.h>

#define B_   2
#define T_   2048
#define HID_ 2048
#define H_   16
#define KVH_ 4
#define D_   128
#define GQ_  (H_ / KVH_)

#define QN_  8388608   // B*T*H*D
#define KN_  2097152   // B*T*KVH*D
#define TOTQ_ 4194304  // B*T*H*D/2  (rope q pairs)
#define TOTK_ 1048576  // B*T*KVH*D/2

typedef unsigned short u16;
typedef __attribute__((ext_vector_type(8))) unsigned short us8v;
typedef __attribute__((ext_vector_type(8))) short s16x8;   // MFMA A/B frag
typedef __attribute__((ext_vector_type(4))) float f32x4;   // MFMA C/D frag

__device__ __forceinline__ float bf2f(u16 u) {
  return __uint_as_float(((unsigned)u) << 16);
}
__device__ __forceinline__ u16 f2bf(float f) {
  unsigned x = __float_as_uint(f);
  return (u16)((x + 0x7fffu + ((x >> 16) & 1u)) >> 16);  // RNE
}

// global(16B per lane) -> LDS direct, wave-uniform dst base + lane*16.
__device__ __forceinline__ void gl2lds(const void* gp, void* lp) {
  __builtin_amdgcn_global_load_lds(
      (const __attribute__((address_space(1))) unsigned int*)gp,
      (__attribute__((address_space(3))) unsigned int*)lp, 16, 0, 0);
}

// ---------------------------------------------------------------------------
// On-device dtype probe (bf16 vs fp32), per tensor.
// ---------------------------------------------------------------------------
__device__ __forceinline__ void probe2(const void* A, const void* W, int tid,
                                       bool* abf, bool* wbf) {
  __shared__ int cA, zA, cW, zW;
  if (tid == 0) { cA = 0; zA = 0; cW = 0; zW = 0; }
  __syncthreads();
  const int i = 16384 + tid;
  {
    const u16 raw = ((const u16*)A)[i];
    const float v = bf2f(raw);
    const bool bad = !(fabsf(v) <= 1e6f) ||
                     (v != 0.0f && fabsf(v) < 1e-10f);
    if (bad) atomicAdd(&cA, 1);
    if (((tid & 1) == 0) && raw == 0) atomicAdd(&zA, 1);
  }
  {
    const u16 raw = ((const u16*)W)[i];
    const float v = bf2f(raw);
    const bool bad = !(fabsf(v) <= 1e6f) ||
                     (v != 0.0f && fabsf(v) < 1e-10f);
    if (bad) atomicAdd(&cW, 1);
    if (((tid & 1) == 0) && raw == 0) atomicAdd(&zW, 1);
  }
  __syncthreads();
  *abf = (cA < 8) && (zA < 100);
  *wbf = (cW < 8) && (zW < 100);
}

// ---------------------------------------------------------------------------
// Transpose body: W[K][N] (bf16 OR fp32, probed) -> WT[N][K] bf16.
// ---------------------------------------------------------------------------
__device__ void transp_body(const void* __restrict__ Wv_,
                            u16* __restrict__ WT, int K, int N, int bx,
                            int by, int tid) {
  bool wbf, dummy;
  probe2(Wv_, Wv_, tid, &wbf, &dummy);

  __shared__ float tile[64][65];
  const int kb = by * 64;
  const int nb = bx * 64;

  for (int it = tid; it < 512; it += 256) {
    const int r = it >> 3;
    const int g = it & 7;
    const size_t off = (size_t)(kb + r) * N + nb + g * 8;
    float f[8];
    if (wbf) {
      const us8v t8 = *(const us8v*)((const u16*)Wv_ + off);
#pragma unroll
      for (int e = 0; e < 8; ++e) f[e] = bf2f(t8[e]);
    } else {
      const float4 f0 = *(const float4*)((const float*)Wv_ + off);
      const float4 f1 = *(const float4*)((const float*)Wv_ + off + 4);
      f[0] = f0.x; f[1] = f0.y; f[2] = f0.z; f[3] = f0.w;
      f[4] = f1.x; f[5] = f1.y; f[6] = f1.z; f[7] = f1.w;
    }
#pragma unroll
    for (int e = 0; e < 8; ++e) tile[r][g * 8 + e] = f[e];
  }
  __syncthreads();
  for (int it = tid; it < 512; it += 256) {
    const int n = it >> 3;
    const int g = it & 7;
    us8v tmp;
#pragma unroll
    for (int e = 0; e < 8; ++e) tmp[e] = f2bf(tile[g * 8 + e][n]);
    *(us8v*)&WT[(size_t)(nb + n) * K + kb + g * 8] = tmp;
  }
}

// ---------------------------------------------------------------------------
// Activation-convert body: x (fp32 OR bf16, probed) -> bf16, 8 elems/thread.
// ---------------------------------------------------------------------------
__device__ void conv_body(const void* __restrict__ in, u16* __restrict__ outb,
                          int cb, int tid) {
  bool ibf, dummy;
  probe2(in, in, tid, &ibf, &dummy);
  const int idx = cb * 256 + tid;
  if (idx >= (QN_ / 8)) return;
  if (ibf) {
    *(us8v*)&outb[(size_t)idx * 8] =
        *(const us8v*)((const u16*)in + (size_t)idx * 8);
  } else {
    const float4 f0 = *(const float4*)((const float*)in + (size_t)idx * 8);
    const float4 f1 = *(const float4*)((const float*)in + (size_t)idx * 8 + 4);
    uint4 w;
    asm("v_cvt_pk_bf16_f32 %0, %1, %2" : "=v"(w.x) : "v"(f0.x), "v"(f0.y));
    asm("v_cvt_pk_bf16_f32 %0, %1, %2" : "=v"(w.y) : "v"(f0.z), "v"(f0.w));
    asm("v_cvt_pk_bf16_f32 %0, %1, %2" : "=v"(w.z) : "v"(f1.x), "v"(f1.y));
    asm("v_cvt_pk_bf16_f32 %0, %1, %2" : "=v"(w.w) : "v"(f1.z), "v"(f1.w));
    *(uint4*)&outb[(size_t)idx * 8] = w;
  }
}

// ---------------------------------------------------------------------------
// Fused prep: all 4 weight transposes + x->bf16 convert in ONE dispatch.
// Ranges: [0,1024) Wq | [1024,1280) Wk | [1280,1536) Wv | [1536,2560) Wo |
// [2560,6656) conv.
// ---------------------------------------------------------------------------
__global__ __launch_bounds__(256) void prep_k(
    const void* __restrict__ Wq, const void* __restrict__ Wk,
    const void* __restrict__ Wv, const void* __restrict__ Wo,
    const void* __restrict__ x, u16* __restrict__ WqT,
    u16* __restrict__ WkT, u16* __restrict__ WvT, u16* __restrict__ WoT,
    u16* __restrict__ xb) {
  const int b = blockIdx.x;
  const int tid = threadIdx.x;
  if (b < 1024) {
    transp_body(Wq, WqT, HID_, H_ * D_, b & 31, b >> 5, tid);
  } else if (b < 1280) {
    const int bb = b - 1024;
    transp_body(Wk, WkT, HID_, KVH_ * D_, bb & 7, bb >> 3, tid);
  } else if (b < 1536) {
    const int bb = b - 1280;
    transp_body(Wv, WvT, HID_, KVH_ * D_, bb & 7, bb >> 3, tid);
  } else if (b < 2560) {
    const int bb = b - 1536;
    transp_body(Wo, WoT, H_ * D_, HID_, bb & 31, bb >> 5, tid);
  } else {
    conv_body(x, xb, b - 2560, tid);
  }
}

// ---------------------------------------------------------------------------
// MFMA GEMM v6 — 8-PHASE 256-row template (T2-free by layout + T3 + T4 + T5).
// C[M,N] = A[M,K] @ W[K,N]; A bf16, WT[N][K] bf16. BM=256, BK=64, 8 waves
// (2M x 4N), per-wave 128 x (BN/4). BN=192 (QKV) / 128 (Wo): both grids =
// 256 blocks = 1/CU, 112/96 KB LDS.
// R9 post-mortem: 2-phase structures pinned at 28-29% MfmaUtil; LDS-read
// pipe (CU-shared, 12cyc/b128) was the top consumer (51%) and the 2-barrier
// lockstep serializes LDS and MFMA sections. This template: (a) per-wave
// 128-row M halves reads/MFMA 0.58->0.46; (b) 4 sub-phases per K-tile
// {ds_read || stage-issue; barrier; lgkm; 12-16 MFMA; barrier} let per-wave
// lgkm stagger so LDS drain overlaps other waves' MFMA; (c) counted vmcnt
// (5/4, never 0 mid-loop) keeps 3 half-tiles in flight across barriers.
// LDS layout [2 buf][2 ks][rows][32]: 64B rows -> bank-conflict-free reads
// (row alternation spans all 32 banks) AND contiguous gl2lds stage units —
// no swizzle anywhere.
// Stage/region schedule (derived, race-free): phases (ks,h) order
// (0,0),(1,0),(0,1),(1,1); region last read: B_k0@ph1, B_k1@ph2, A_k0@ph3,
// A_k1@ph4; stages: ph1: A_k1(t+1)->buf^1(dead); ph3: B(t+2)->buf (B freed
// ph2); ph4: A_k0(t+2)->buf (A_k0 freed ph3). Steady in-flight at tile end
// = B(t+2)+A_k0(t+2) = (BN/64)+2 loads -> vmcnt(5)/(4).
// OMODE: 0 = fp32 out; 3 = fused QKV epilogue (qbuf/kbuf/vT split).
// ---------------------------------------------------------------------------
template <int OMODE, int BN>
__global__ __launch_bounds__(512, 2) void gemm_8ph(
    const u16* __restrict__ Ab, const u16* __restrict__ WT,
    void* __restrict__ Cv, int M, int N, int K) {
  constexpr int NI = BN / 64;       // n-frags per wave (3 or 2)
  constexpr int CPS = BN / 16;      // B 512-elem chunks per ks sub-buffer
  constexpr int BLT = BN / 64;      // B loads/thread per K-tile (3 or 2)

  const int tid = threadIdx.x;
  __shared__ __align__(16) u16 Alds[2][2][256 * 32];
  __shared__ __align__(16) u16 Blds[2][2][BN * 32];

  const int m0 = blockIdx.y * 256;
  const int n0 = blockIdx.x * BN;
  const int wave = tid >> 6;        // 0..7
  const int lane = tid & 63;
  const int wm = wave >> 2;         // m-half (128 rows)
  const int wn = wave & 3;          // n-slice (BN/4)
  const int l15 = lane & 15;
  const int lq = lane >> 4;

  f32x4 acc[8][NI] = {};
  s16x8 bfr[2][NI];

  const int NT = K >> 6;

  // ---- stage helpers: contiguous 512-elem chunks, wave-uniform LDS base --
  auto stageA = [&](int buf, int ks, int kk) {
#pragma unroll
    for (int p = 0; p < 2; ++p) {
      const int c = wave + p * 8;                 // 0..15 over [256][32]
      const int row = c * 16 + (lane >> 2);
      const int col = (lane & 3) * 8;
      gl2lds(Ab + (size_t)(m0 + row) * K + kk + ks * 32 + col,
             &Alds[buf][ks][c * 512]);
    }
  };
  auto stageB = [&](int buf, int kk) {            // both ks halves
#pragma unroll
    for (int p = 0; p < BLT; ++p) {
      const int c = wave + p * 8;                 // 0..(2*CPS-1)
      const int ks = c / CPS;
      const int lc = c % CPS;
      const int row = lc * 16 + (lane >> 2);
      const int col = (lane & 3) * 8;
      gl2lds(WT + (size_t)(n0 + row) * K + kk + ks * 32 + col,
             &Blds[buf][ks][lc * 512]);
    }
  };

#define VM_STEADY()                                                      \
  do {                                                                   \
    if constexpr (BN == 192)                                             \
      asm volatile("s_waitcnt vmcnt(5)" ::: "memory");                   \
    else                                                                 \
      asm volatile("s_waitcnt vmcnt(4)" ::: "memory");                   \
  } while (0)

#define PHASE(ksv, hv, STAGE_STMT, END_STMT)                             \
  {                                                                      \
    s16x8 af[4];                                                         \
    _Pragma("unroll") for (int mi = 0; mi < 4; ++mi)                     \
      af[mi] = *(const s16x8*)&Alds[b][ksv][                             \
          (wm * 128 + ((hv)*4 + mi) * 16 + l15) * 32 + lq * 8];          \
    if ((hv) == 0) {                                                     \
      _Pragma("unroll") for (int ni = 0; ni < NI; ++ni)                  \
        bfr[ksv][ni] = *(const s16x8*)&Blds[b][ksv][                     \
            (wn * (BN / 4) + ni * 16 + l15) * 32 + lq * 8];              \
    }                                                                    \
    STAGE_STMT;                                                          \
    __builtin_amdgcn_sched_barrier(0);                                   \
    __builtin_amdgcn_s_barrier();                                        \
    asm volatile("s_waitcnt lgkmcnt(0)" ::: "memory");                   \
    __builtin_amdgcn_sched_barrier(0);                                   \
    __builtin_amdgcn_s_setprio(1);                                       \
    _Pragma("unroll") for (int mi = 0; mi < 4; ++mi)                     \
      _Pragma("unroll") for (int ni = 0; ni < NI; ++ni)                  \
        acc[(hv)*4 + mi][ni] = __builtin_amdgcn_mfma_f32_16x16x32_bf16(  \
            af[mi], bfr[ksv][ni], acc[(hv)*4 + mi][ni], 0, 0, 0);        \
    __builtin_amdgcn_s_setprio(0);                                       \
    END_STMT;                                                            \
    __builtin_amdgcn_sched_barrier(0);                                   \
    __builtin_amdgcn_s_barrier();                                        \
  }

  // ---- prologue: tile0 full + tile1 {B, A_k0}; keep tile1's in flight ----
  stageA(0, 0, 0);
  stageA(0, 1, 0);
  stageB(0, 0);
  stageB(1, 64);
  stageA(1, 0, 64);
  VM_STEADY();
  __builtin_amdgcn_sched_barrier(0);
  __builtin_amdgcn_s_barrier();

  for (int t = 0; t < NT; ++t) {
    const int b = t & 1;
    const int kk1 = (t + 1) << 6;
    const int kk2 = (t + 2) << 6;
    const bool s1 = (t + 1) < NT;
    const bool s2 = (t + 2) < NT;

    // ph1 (ks0, mh0): + stage A_k1(t+1) -> dead buffer
    PHASE(0, 0, { if (s1) stageA(b ^ 1, 1, kk1); }, {});
    // ph2 (ks1, mh0)
    PHASE(1, 0, {}, {});
    // ph3 (ks0, mh1): + stage B(t+2) -> this buffer (B freed after ph2)
    PHASE(0, 1, { if (s2) stageB(b, kk2); }, {});
    // ph4 (ks1, mh1): + stage A_k0(t+2); counted vmcnt at tile end
    PHASE(1, 1, { if (s2) stageA(b, 0, kk2); },
          {
            if (s2) {
              VM_STEADY();
            } else if (s1) {
              asm volatile("s_waitcnt vmcnt(0)" ::: "memory");
            }
          });
  }
#undef PHASE
#undef VM_STEADY

  // ---- epilogue: D col=lane&15, row=quad*4+reg ----
#pragma unroll
  for (int mf = 0; mf < 8; ++mf) {
#pragma unroll
    for (int ni = 0; ni < NI; ++ni) {
      const int row0 = m0 + wm * 128 + mf * 16 + lq * 4;
      const int col = n0 + wn * (BN / 4) + ni * 16 + l15;
#pragma unroll
      for (int r = 0; r < 4; ++r) {
        const int row = row0 + r;
        if (OMODE == 0) {
          ((float*)Cv)[(size_t)row * N + col] = acc[mf][ni][r];
        } else {
          const u16 val = f2bf(acc[mf][ni][r]);
          if (col < 2048) {
            ((u16*)Cv)[(size_t)row * 2048 + col] = val;           // qbuf
          } else if (col < 2560) {
            ((u16*)Cv)[QN_ + (size_t)row * 512 + (col - 2048)] = val;  // kbuf
          } else {
            const int c = col - 2560;          // 0..511
            const int kvh = c >> 7;
            const int d = c & 127;
            const int bb = row >> 11;          // T_ == 2048
            const int tt = row & (T_ - 1);
            ((u16*)Cv)[QN_ + KN_ +
                       ((size_t)(bb * KVH_ + kvh) * D_ + d) * T_ + tt] = val;
          }
        }
      }
    }
  }
}

// ---------------------------------------------------------------------------
// Fused RoPE (Q and K in one dispatch). Q pre-scaled by 1/sqrt(D).
// ---------------------------------------------------------------------------
__global__ __launch_bounds__(256) void rope2(u16* __restrict__ qb,
                                             u16* __restrict__ kb,
                                             const void* __restrict__ cosT,
                                             const void* __restrict__ sinT) {
  const int tid = threadIdx.x;
  bool cbf, sbf;
  probe2(cosT, sinT, tid, &cbf, &sbf);

  int idx = blockIdx.x * 256 + tid;
  u16* t;
  int NH;
  float qs;
  if (idx < TOTQ_) {
    t = qb; NH = H_; qs = 0.08838834764831845f;
  } else {
    idx -= TOTQ_;
    if (idx >= TOTK_) return;
    t = kb; NH = KVH_; qs = 1.0f;
  }
  const int d = idx & 63;
  const int rest = idx >> 6;
  const int tt = (rest / NH) % T_;
  const size_t base = (size_t)rest * D_;
  const int ci = tt * D_ + d;
  float c1, s1, c2, s2;
  if (cbf) {
    c1 = bf2f(((const u16*)cosT)[ci]);
    c2 = bf2f(((const u16*)cosT)[ci + 64]);
  } else {
    c1 = ((const float*)cosT)[ci];
    c2 = ((const float*)cosT)[ci + 64];
  }
  if (sbf) {
    s1 = bf2f(((const u16*)sinT)[ci]);
    s2 = bf2f(((const u16*)sinT)[ci + 64]);
  } else {
    s1 = ((const float*)sinT)[ci];
    s2 = ((const float*)sinT)[ci + 64];
  }
  const float x1 = bf2f(t[base + d]);
  const float x2 = bf2f(t[base + d + 64]);
  t[base + d] = f2bf((x1 * c1 - x2 * s1) * qs);
  t[base + d + 64] = f2bf((x2 * c2 + x1 * s2) * qs);
}

// ---------------------------------------------------------------------------
// Causal GQA flash attention, MFMA v4 (unchanged, passing):
// swapped QK^T (lane-local softmax), paired q-tiles, 8 waves, dbuf
// global_load_lds staging, defer-max, setprio.
// ---------------------------------------------------------------------------
#define ATT_STAGE(bi, ktile)                                                  \
  do {                                                                        \
    const int _k0 = (ktile) * 64;                                             \
    u16* _bk = &SM[(bi) * 16384];                                             \
    _Pragma("unroll") for (int _p = 0; _p < 2; ++_p) {                        \
      const int _it = tid + _p * 512;                                         \
      const int _r = _it >> 4, _s = _it & 15;                                 \
      gl2lds(kp + (size_t)(_k0 + _r) * (KVH_ * D_) + ((_s ^ (_r & 7)) * 8),   \
             &_bk[((tid & ~63) + _p * 512) * 8]);                             \
    }                                                                         \
    _Pragma("unroll") for (int _p = 0; _p < 2; ++_p) {                        \
      const int _it = tid + _p * 512;                                         \
      const int _r = _it >> 3, _s = _it & 7;                                  \
      gl2lds(vp + (size_t)_r * T_ + _k0 + ((_s ^ (_r & 7)) * 8),              \
             &_bk[8192 + ((tid & ~63) + _p * 512) * 8]);                      \
    }                                                                         \
  } while (0)

__global__ __launch_bounds__(512, 4) void attn_mfma(
    const u16* __restrict__ q, const u16* __restrict__ k,
    const u16* __restrict__ vT, u16* __restrict__ o) {
  const int tid = threadIdx.x;
  const int ip = blockIdx.y;                 // pair index 0..15
  const int bh = blockIdx.x;
  const int b = bh >> 4;
  const int h = bh & 15;
  const int kvh = h >> 2;
  const int hi0 = 64 * (31 - ip);
  const int lo0 = 64 * ip;

  __shared__ __align__(16) u16 SM[2 * 16384];  // dbuf {Ks 64x128, Vt 128x64}
  __shared__ __align__(16) u16 Pl[128 * 64];   // P (bf16), granule-XOR

  const int wave = tid >> 6;                 // 0..7
  const int lane = tid & 63;
  const int l15 = lane & 15;
  const int quad = lane >> 4;
  const bool isHi = wave < 4;
  const int rowbase = isHi ? (hi0 + 16 * wave) : (lo0 + 16 * (wave - 4));
  const int pr0 = 16 * wave;                 // Pl row base, wave-private

  const u16* kp = k + ((size_t)b * T_ * KVH_ + kvh) * D_;
  const u16* vp = vT + (size_t)(b * KVH_ + kvh) * D_ * T_;

  // Q fragment, reg-resident: B-layout [n=q=l15][d=st*32+quad*8+j].
  s16x8 qf[4];
  {
    const size_t qrow = ((size_t)(b * T_ + rowbase + l15) * H_ + h) * D_;
#pragma unroll
    for (int st = 0; st < 4; ++st)
      qf[st] = *(const s16x8*)&q[qrow + st * 32 + quad * 8];
  }

  f32x4 acc_o[8] = {};   // PV out: row q=quad*4+r, col d=nt2*16+l15
  float m_s = -1.0e30f, l_s = 0.0f;   // per-lane state for q = rowbase+l15

  const int nkt = 32 - ip;  // hi tile count; lo active while kt <= ip

  ATT_STAGE(0, 0);
  __syncthreads();

  for (int kt = 0; kt < nkt; ++kt) {
    const int k0 = kt * 64;
    const u16* Ks = &SM[(kt & 1) * 16384];
    const u16* Vt = Ks + 8192;

    if (kt + 1 < nkt) ATT_STAGE((kt + 1) & 1, kt + 1);

    const bool active = isHi || (kt <= ip);  // wave-uniform
    if (active) {
      // ---- swapped QK^T: lane holds S[q=l15][k=nt*16+quad*4+r] ----
      f32x4 accs[4] = {};
      __builtin_amdgcn_s_setprio(1);
#pragma unroll
      for (int st = 0; st < 4; ++st) {
        const int g = st * 4 + quad;
#pragma unroll
        for (int nt = 0; nt < 4; ++nt) {
          const int row = nt * 16 + l15;
          const s16x8 kf =
              *(const s16x8*)&Ks[row * 128 + ((g ^ (row & 7)) << 3)];
          accs[nt] = __builtin_amdgcn_mfma_f32_16x16x32_bf16(kf, qf[st],
                                                             accs[nt], 0, 0,
                                                             0);
        }
      }
      __builtin_amdgcn_s_setprio(0);

      // ---- causal mask: wave-uniform branch, rare ----
      if ((k0 + 63) > rowbase) {
        const int qg = rowbase + l15;
#pragma unroll
        for (int nt = 0; nt < 4; ++nt)
#pragma unroll
          for (int r = 0; r < 4; ++r)
            if (qg < (k0 + nt * 16 + quad * 4 + r)) accs[nt][r] = -1.0e30f;
      }

      // ---- row max: in-lane tree + 2 shfl ----
      float t0 = fmaxf(fmaxf(accs[0][0], accs[0][1]),
                       fmaxf(accs[0][2], accs[0][3]));
      float t1 = fmaxf(fmaxf(accs[1][0], accs[1][1]),
                       fmaxf(accs[1][2], accs[1][3]));
      float t2 = fmaxf(fmaxf(accs[2][0], accs[2][1]),
                       fmaxf(accs[2][2], accs[2][3]));
      float t3 = fmaxf(fmaxf(accs[3][0], accs[3][1]),
                       fmaxf(accs[3][2], accs[3][3]));
      float mx = fmaxf(fmaxf(t0, t1), fmaxf(t2, t3));
      mx = fmaxf(mx, __shfl_xor(mx, 16));
      mx = fmaxf(mx, __shfl_xor(mx, 32));

      // ---- defer-max (T13) ----
      const int defer = __all(mx <= m_s + 8.0f);
      float alv = 1.0f;
      if (!defer) {
        const float mnew = fmaxf(m_s, mx);
        alv = __expf(m_s - mnew);
        m_s = mnew;
      }

      // ---- exp ----
#pragma unroll
      for (int nt = 0; nt < 4; ++nt)
#pragma unroll
        for (int r = 0; r < 4; ++r)
          accs[nt][r] = __expf(accs[nt][r] - m_s);

      // ---- pack + write P early (ds latency overlaps the sum) ----
#pragma unroll
      for (int nt = 0; nt < 4; ++nt) {
        uint2 w;
        asm("v_cvt_pk_bf16_f32 %0, %1, %2"
            : "=v"(w.x) : "v"(accs[nt][0]), "v"(accs[nt][1]));
        asm("v_cvt_pk_bf16_f32 %0, %1, %2"
            : "=v"(w.y) : "v"(accs[nt][2]), "v"(accs[nt][3]));
        const int prow = pr0 + l15;
        const int c0 = nt * 16 + quad * 4;
        *(uint2*)&Pl[prow * 64 + (((c0 >> 3) ^ (prow & 7)) << 3) + (c0 & 7)] =
            w;
      }

      // ---- row sum + state update ----
      float s0 = (accs[0][0] + accs[0][1]) + (accs[0][2] + accs[0][3]);
      float s1 = (accs[1][0] + accs[1][1]) + (accs[1][2] + accs[1][3]);
      float s2 = (accs[2][0] + accs[2][1]) + (accs[2][2] + accs[2][3]);
      float s3 = (accs[3][0] + accs[3][1]) + (accs[3][2] + accs[3][3]);
      float rs = (s0 + s1) + (s2 + s3);
      rs += __shfl_xor(rs, 16);
      rs += __shfl_xor(rs, 32);
      l_s = l_s * alv + rs;

      // ---- O rescale (only when max grew; al redistributed to PV rows) ----
      if (!defer) {
#pragma unroll
        for (int r = 0; r < 4; ++r) {
          const float a4 = __shfl(alv, 4 * quad + r);
#pragma unroll
          for (int nt2 = 0; nt2 < 8; ++nt2) acc_o[nt2][r] *= a4;
        }
      }

      asm volatile("s_waitcnt lgkmcnt(0)" ::: "memory");
      __builtin_amdgcn_sched_barrier(0);

      // ---- PV: O[16q x 128d] += P[16x64] @ V[64x128] ----
      s16x8 pa[2];
#pragma unroll
      for (int ks = 0; ks < 2; ++ks) {
        const int row = pr0 + l15;
        const int g = ks * 4 + quad;
        pa[ks] = *(const s16x8*)&Pl[row * 64 + ((g ^ (row & 7)) << 3)];
      }
      __builtin_amdgcn_s_setprio(1);
#pragma unroll
      for (int ks = 0; ks < 2; ++ks) {
        const int g = ks * 4 + quad;
#pragma unroll
        for (int nt2 = 0; nt2 < 8; ++nt2) {
          const int row = nt2 * 16 + l15;
          const s16x8 vf =
              *(const s16x8*)&Vt[row * 64 + ((g ^ (row & 7)) << 3)];
          acc_o[nt2] = __builtin_amdgcn_mfma_f32_16x16x32_bf16(pa[ks], vf,
                                                               acc_o[nt2], 0,
                                                               0, 0);
        }
      }
      __builtin_amdgcn_s_setprio(0);
    }

    __syncthreads();  // drains vmcnt: buf^1 staged; all LDS reads retired
  }

  // ---- epilogue: normalize + store (linv redistributed to PV rows) ----
  const float inv = 1.0f / l_s;
#pragma unroll
  for (int r = 0; r < 4; ++r) {
    const float linv = __shfl(inv, 4 * quad + r);
    const size_t orow =
        ((size_t)(b * T_ + rowbase + quad * 4 + r) * H_ + h) * D_;
#pragma unroll
    for (int nt2 = 0; nt2 < 8; ++nt2)
      o[orow + nt2 * 16 + l15] = f2bf(acc_o[nt2][r] * linv);
  }
}

// Fallback: zero d_out (fp32) so an undersized workspace fails cleanly.
__global__ void zero_out_k(float* __restrict__ out, int n) {
  const int i = blockIdx.x * blockDim.x + threadIdx.x;
  if (i < n) out[i] = 0.0f;
}

// ---------------------------------------------------------------------------
extern "C" void kernel_launch(void* const* d_in, const int* in_sizes, int n_in,
                              void* d_out, int out_size, void* d_ws,
                              size_t ws_size, hipStream_t stream) {
  const void* x    = d_in[0];
  const void* cosT = d_in[1];
  const void* sinT = d_in[2];
  const void* Wq   = d_in[3];
  const void* Wk   = d_in[4];
  const void* Wv   = d_in[5];
  const void* Wo   = d_in[6];
  float* out = (float*)d_out;

  // Workspace (bf16 elems): qbuf QN | kbuf KN | vbufT KN | obuf QN |
  //   WqT 4194304 | WkT 1048576 | WvT 1048576 | WoT 4194304  = 60 MiB.
  // xb (bf16 copy of x, QN elems) ALIASES obuf: x is consumed by the QKV
  // GEMM, which completes before attention writes obuf (stream-ordered).
  const size_t QN = QN_;
  const size_t KN = KN_;
  const size_t WQT = (size_t)HID_ * (H_ * D_);     // 4194304
  const size_t WKT = (size_t)HID_ * (KVH_ * D_);   // 1048576
  const size_t need = (2 * QN + 2 * KN + 2 * WQT + 2 * WKT) * sizeof(u16);
  if (ws_size < need) {
    zero_out_k<<<(out_size + 255) / 256, 256, 0, stream>>>(out, out_size);
    return;
  }

  u16* qbuf  = (u16*)d_ws;
  u16* kbuf  = qbuf + QN;
  u16* vbufT = kbuf + KN;    // V^T: [b][kvh][d][t]
  u16* obuf  = vbufT + KN;
  u16* xb    = obuf;         // alias (see above)
  u16* WqT   = obuf + QN;    // WqT|WkT|WvT contiguous => fused-QKV WT[3072][K]
  u16* WkT   = WqT + WQT;
  u16* WvT   = WkT + WKT;
  u16* WoT   = WvT + WKT;

  const int M = B_ * T_;  // 4096

  // 1) Fused prep: 4 transposes + x->bf16 (one dispatch).
  prep_k<<<6656, 256, 0, stream>>>(Wq, Wk, Wv, Wo, x, WqT, WkT, WvT, WoT, xb);

  // 2) Fused QKV projection: N = 2048(Q)+512(K)+512(V^T). 8-phase 256x192
  //    tile -> grid 16x16 = 256 blocks = 1/CU.
  gemm_8ph<3, 192><<<dim3(3072 / 192, M / 256), dim3(512), 0, stream>>>(
      xb, WqT, qbuf, M, 3072, HID_);

  // 3) Fused RoPE (Q scaled by 1/sqrt(D), K unscaled) — one dispatch.
  rope2<<<(TOTQ_ + TOTK_) / 256, 256, 0, stream>>>(qbuf, kbuf, cosT, sinT);

  // 4) MFMA flash attention v4 (swapped QK^T, lane-local softmax).
  attn_mfma<<<dim3(B_ * H_, 16), dim3(512), 0, stream>>>(
      qbuf, kbuf, vbufT, obuf);

  // 5) Output projection (fp32 out). 8-phase 256x128 tile -> 16x16 grid.
  gemm_8ph<0, 128><<<dim3(HID_ / 128, M / 256), dim3(512), 0, stream>>>(
      obuf, WoT, out, M, HID_, H_ * D_);
}